// Round 9
// baseline (239.905 us; speedup 1.0000x reference)
//
#include <hip/hip_runtime.h>
#include <stdint.h>

typedef unsigned short u16;
typedef __attribute__((ext_vector_type(8))) __bf16 bf16x8;
typedef __attribute__((ext_vector_type(4))) float f32x4;

__device__ __forceinline__ u16 f2bf(float f) {
  unsigned u = __float_as_uint(f);
  u += 0x7FFF + ((u >> 16) & 1);   // RNE
  return (u16)(u >> 16);
}

__device__ __forceinline__ float bf2f(u16 h) {
  return __uint_as_float(((unsigned)h) << 16);
}

__device__ __forceinline__ void llds16(const u16* g, u16* l) {
  __builtin_amdgcn_global_load_lds(
      (const __attribute__((address_space(1))) void*)g,
      (__attribute__((address_space(3))) void*)l, 16, 0, 0);
}

// ---------------------------------------------------------------------------
// fused cast fp32 -> bf16 for x | wq | wk | wv + zero lsum
// ---------------------------------------------------------------------------
__global__ __launch_bounds__(256) void cast_all(
    const float* __restrict__ x, const float* __restrict__ wq,
    const float* __restrict__ wk, const float* __restrict__ wv,
    u16* __restrict__ xb, u16* __restrict__ wb, float* __restrict__ lsum) {
  int i = blockIdx.x * 256 + threadIdx.x;
  if (i < 8192) lsum[i] = 0.f;        // softmax-denominator accumulator
  const float* src; u16* dst; int off;
  if (i < 2097152)      { src = x;  dst = xb;            off = i; }
  else if (i < 2359296) { src = wq; dst = wb;            off = i - 2097152; }
  else if (i < 2621440) { src = wk; dst = wb + 1048576;  off = i - 2359296; }
  else                  { src = wv; dst = wb + 2097152;  off = i - 2621440; }
  float4 f = ((const float4*)src)[off];
  ushort4 o;
  o.x = f2bf(f.x); o.y = f2bf(f.y); o.z = f2bf(f.z); o.w = f2bf(f.w);
  ((ushort4*)dst)[off] = o;
}

// ---------------------------------------------------------------------------
// QKV GEMM (r0-verbatim gemm_nt, MODE 0 only): C[M,N] = A[M,K] * B[N,K]^T.
// 128x128 tile, BK=64, 256 threads = 4 waves (2x2), each wave 64x64 via 4x4
// mfma_f32_16x16x32_bf16, 2 k-steps/iter.  global_load_lds width-16 staging.
// LDS chunk-XOR swizzle -> SQ_LDS_BANK_CONFLICT == 0 measured.
// Kept as its OWN template: r5's shared-wrapper refactor pushed VGPR 80->116
// (rule #19); this verbatim form measured 80 VGPR / 66.6us (r8 control).
// ---------------------------------------------------------------------------
template<int MODE>
__global__ __launch_bounds__(256) void gemm_nt(
    const u16* __restrict__ A, long long sA, int lda,
    const u16* __restrict__ B, long long sB, int ldb,
    void* __restrict__ Cp, long long sC, int ldc,
    int K, u16* __restrict__ vt, float scale,
    float* __restrict__ lsum, const int* __restrict__ causalp) {
  const int t = threadIdx.x;
  const int causal = (MODE == 0) ? 1 : causalp[0];

  int rt = blockIdx.x, ct = blockIdx.y;

  const int rowbase = rt * 128;
  const int colbase = ct * 128;
  const u16* Ab = A + (long long)blockIdx.z * sA;
  const u16* Bb = B + (long long)blockIdx.z * sB;

  int Keff = K;
  if (MODE == 2 && causal) Keff = min(K, rowbase + 128);

  __shared__ u16 As[8192];   // [128][64] u16, chunk-swizzled
  __shared__ u16 Bs[8192];

  const int lane = t & 63;
  const int wv = t >> 6;
  const int wr = wv >> 1;
  const int wc = wv & 1;
  const int quad = lane >> 4;
  const int lr = lane & 15;

  f32x4 acc[4][4];
  const f32x4 zero = {0.f, 0.f, 0.f, 0.f};
#pragma unroll
  for (int i = 0; i < 4; ++i)
#pragma unroll
    for (int j = 0; j < 4; ++j) acc[i][j] = zero;

  {
    const int csw = (t & 7) ^ ((t >> 3) & 7);
    const u16* ga = Ab + (long long)(rowbase + (t >> 3)) * lda + csw * 8;
    const u16* gb = Bb + (long long)(colbase + (t >> 3)) * ldb + csw * 8;
    const long long ra = 32LL * lda, rb = 32LL * ldb;
    u16* la = As + t * 8;
    u16* lb = Bs + t * 8;

    const int m7 = lr & 7;
    const int a_base = (wr * 64 + lr) * 64 + ((quad ^ m7) * 8);
    const int b_base = (wc * 64 + lr) * 64 + ((quad ^ m7) * 8);

    for (int k0 = 0; k0 < Keff; k0 += 64) {
      __syncthreads();               // prior frag reads done before overwrite
#pragma unroll
      for (int i = 0; i < 4; ++i) {
        llds16(ga + k0 + i * ra, la + i * 2048);
        llds16(gb + k0 + i * rb, lb + i * 2048);
      }
      __syncthreads();               // compiler drains vmcnt before barrier
#pragma unroll
      for (int ks = 0; ks < 2; ++ks) {
        const int ko = ks ? 32 : 0;  // slot ^= 4  ->  u16 offset ^ 32
        bf16x8 af[4], bfv[4];
#pragma unroll
        for (int tm = 0; tm < 4; ++tm)
          af[tm] = *(const bf16x8*)(As + ((a_base + tm * 1024) ^ ko));
#pragma unroll
        for (int tn = 0; tn < 4; ++tn)
          bfv[tn] = *(const bf16x8*)(Bs + ((b_base + tn * 1024) ^ ko));
#pragma unroll
        for (int tm = 0; tm < 4; ++tm)
#pragma unroll
          for (int tn = 0; tn < 4; ++tn)
            acc[tm][tn] = __builtin_amdgcn_mfma_f32_16x16x32_bf16(
                af[tm], bfv[tn], acc[tm][tn], 0, 0, 0);
      }
    }
  }

  // ------------------------------ epilogue ------------------------------
  if (MODE == 0 && colbase >= 2048) {
#pragma unroll
    for (int tm = 0; tm < 4; ++tm) {
      int s0 = rowbase + wr * 64 + tm * 16 + quad * 4;
      int b = s0 >> 11;
      int sl = s0 & 2047;
#pragma unroll
      for (int tn = 0; tn < 4; ++tn) {
        int e = colbase - 2048 + wc * 64 + tn * 16 + lr;
        ushort4 o;
        o.x = f2bf(acc[tm][tn][0]);
        o.y = f2bf(acc[tm][tn][1]);
        o.z = f2bf(acc[tm][tn][2]);
        o.w = f2bf(acc[tm][tn][3]);
        *(ushort4*)(vt + ((long long)(b * 1024 + e)) * 2048 + sl) = o;
      }
    }
    return;
  }

#pragma unroll
  for (int tm = 0; tm < 4; ++tm) {
#pragma unroll
    for (int r = 0; r < 4; ++r) {
      const int grow = rowbase + wr * 64 + tm * 16 + quad * 4 + r;
      float li, rsum = 0.f;
      if (MODE == 2) li = __builtin_amdgcn_rcpf(lsum[blockIdx.z * 2048 + grow]);
#pragma unroll
      for (int tn = 0; tn < 4; ++tn) {
        const int gcol = colbase + wc * 64 + tn * 16 + lr;
        float val = acc[tm][tn][r];
        if (MODE == 0) {
          ((u16*)Cp)[(long long)grow * ldc + gcol] = f2bf(val);
        } else if (MODE == 1) {
          u16* C = (u16*)Cp + (long long)blockIdx.z * sC;
          float ex = (causal && gcol > grow) ? 0.f : __expf(val * scale);
          C[(long long)grow * ldc + gcol] = f2bf(ex);
          rsum += ex;
        } else {
          float* C = (float*)Cp + (long long)blockIdx.z * sC;
          C[(long long)grow * ldc + gcol] = val * li;
        }
      }
      if (MODE == 1) {
#pragma unroll
        for (int o = 8; o > 0; o >>= 1) rsum += __shfl_xor(rsum, o, 64);
        if (lr == 0)
          atomicAdd(&lsum[blockIdx.z * 2048 + grow], rsum);
      }
    }
  }
}

// ---------------------------------------------------------------------------
// sc/pv core, round-9: 512 threads = 8 waves (2M x 4N), 128x128 tile, BK=64,
// double-buffered.  Rationale: sc measured (r6) MfmaUtil 10.6 / VALUBusy 8.3
// / occupancy 13% at 2.1 blocks/CU x 4 waves = 8.5 waves/CU — latency-bound
// on wave-TLP (QKV runs the same loop at 24 waves/CU and 3x the MfmaUtil).
// 8-wave blocks double waves/CU to ~17 with traffic UNCHANGED (tile split
// would have doubled A-fetch).  Per wave: 64x32 sub-tile, acc[4][2],
// 8 MFMA / 6 ds_read per ks.  Staging: 512 thr cover 64 rows per llds16
// call (2 calls per operand); row&7 == (t>>3)&7 holds (64 % 8 == 0) so the
// chunk-XOR swizzle is unchanged.  Queues dropped (r8: queue with jobs ==
// resident blocks degenerates to 1 job/block, randomizes locality, cost
// ~9us on pv).
// MODE 1: scores -> exp(s*scale) fused, causal -> 0, row-sums atomicAdd
// MODE 2: PV -> fp32, * rcp(lsum[row]), causal K-truncation
// ---------------------------------------------------------------------------
template<int MODE>
__device__ __forceinline__ void gemm_core8(
    int rt, int ct, int zb, int causal, u16* As, u16* Bs,
    const u16* __restrict__ A, long long sA, int lda,
    const u16* __restrict__ B, long long sB, int ldb,
    void* __restrict__ Cp, long long sC, int ldc,
    int K, float scale, float* __restrict__ lsum) {
  const int t = threadIdx.x;

  const int rowbase = rt * 128;
  const int colbase = ct * 128;
  const u16* Ab = A + (long long)zb * sA;
  const u16* Bb = B + (long long)zb * sB;

  int Keff = K;
  if (MODE == 2 && causal) Keff = min(K, rowbase + 128);

  const int lane = t & 63;
  const int wv = t >> 6;          // 0..7
  const int wr = wv >> 2;         // 0..1  (64 rows each)
  const int wc = wv & 3;          // 0..3  (32 cols each)
  const int quad = lane >> 4;
  const int lr = lane & 15;

  f32x4 acc[4][2];
  const f32x4 zero = {0.f, 0.f, 0.f, 0.f};
#pragma unroll
  for (int i = 0; i < 4; ++i)
#pragma unroll
    for (int j = 0; j < 2; ++j) acc[i][j] = zero;

  {
    // staging: 512 threads; thread t covers row (t>>3) + i*64, slot (t&7);
    // fetches global chunk csw = (t&7)^((t>>3)&7) of its row so the linear
    // DMA write yields slot = chunk^(row&7)  (row&7 == (t>>3)&7, 64%8==0).
    const int csw = (t & 7) ^ ((t >> 3) & 7);
    const u16* ga = Ab + (long long)(rowbase + (t >> 3)) * lda + csw * 8;
    const u16* gb = Bb + (long long)(colbase + (t >> 3)) * ldb + csw * 8;
    const long long ra = 64LL * lda, rb = 64LL * ldb;
    u16* la = As + t * 8;
    u16* lb = Bs + t * 8;

    const int m7 = lr & 7;
    const int a_base = (wr * 64 + lr) * 64 + ((quad ^ m7) * 8);
    const int b_base = (wc * 32 + lr) * 64 + ((quad ^ m7) * 8);

    // ---- 2-phase double-buffered pipeline (buffers 8192 u16 apart) ----
#pragma unroll
    for (int i = 0; i < 2; ++i) {   // prologue: stage k=0 into buf0
      llds16(ga + i * ra, la + i * 4096);
      llds16(gb + i * rb, lb + i * 4096);
    }
    __syncthreads();
    for (int k0 = 0; k0 < Keff; k0 += 64) {
      const int nb = ((k0 >> 6) & 1) ^ 1;       // prefetch buffer
      const int bo = (nb ^ 1) << 13;            // current buffer offset
      if (k0 + 64 < Keff) {
#pragma unroll
        for (int i = 0; i < 2; ++i) {           // issue next-tile loads
          llds16(ga + (k0 + 64) + i * ra, la + nb * 8192 + i * 4096);
          llds16(gb + (k0 + 64) + i * rb, lb + nb * 8192 + i * 4096);
        }
      }
#pragma unroll
      for (int ks = 0; ks < 2; ++ks) {          // compute current buffer
        const int ko = ks ? 32 : 0;
        bf16x8 af[4], bfv[2];
#pragma unroll
        for (int tm = 0; tm < 4; ++tm)
          af[tm] = *(const bf16x8*)(As + bo + ((a_base + tm * 1024) ^ ko));
#pragma unroll
        for (int tn = 0; tn < 2; ++tn)
          bfv[tn] = *(const bf16x8*)(Bs + bo + ((b_base + tn * 1024) ^ ko));
#pragma unroll
        for (int tm = 0; tm < 4; ++tm)
#pragma unroll
          for (int tn = 0; tn < 2; ++tn)
            acc[tm][tn] = __builtin_amdgcn_mfma_f32_16x16x32_bf16(
                af[tm], bfv[tn], acc[tm][tn], 0, 0, 0);
      }
      __syncthreads();   // drains prefetch (vmcnt0) + orders buffer reuse
    }
  }

  // ------------------------------ epilogue ------------------------------
#pragma unroll
  for (int tm = 0; tm < 4; ++tm) {
#pragma unroll
    for (int r = 0; r < 4; ++r) {
      const int grow = rowbase + wr * 64 + tm * 16 + quad * 4 + r;
      float li, rsum = 0.f;
      if (MODE == 2) li = __builtin_amdgcn_rcpf(lsum[zb * 2048 + grow]);
#pragma unroll
      for (int tn = 0; tn < 2; ++tn) {
        const int gcol = colbase + wc * 32 + tn * 16 + lr;
        float val = acc[tm][tn][r];
        if (MODE == 1) {
          u16* C = (u16*)Cp + (long long)zb * sC;
          float ex = (causal && gcol > grow) ? 0.f : __expf(val * scale);
          C[(long long)grow * ldc + gcol] = f2bf(ex);
          rsum += ex;
        } else {
          float* C = (float*)Cp + (long long)zb * sC;
          C[(long long)grow * ldc + gcol] = val * li;
        }
      }
      if (MODE == 1) {
        // partial row-sum over this wave's 32 cols: reduce the 16 lr lanes,
        // one atomic per (row, wave-col-group)
#pragma unroll
        for (int o = 8; o > 0; o >>= 1) rsum += __shfl_xor(rsum, o, 64);
        if (lr == 0)
          atomicAdd(&lsum[zb * 2048 + grow], rsum);
      }
    }
  }
}

// ---------------------------------------------------------------------------
// scores: P' = exp((Q @ K^T)/32), causal -> lower-tri tiles only, bf16 out;
// row sums -> lsum via atomics.  Static decode, 512-thread blocks.
// Grid 1024: causal uses j<544 (4 x 136 lower-tri), rest return instantly.
// ---------------------------------------------------------------------------
__global__ __launch_bounds__(512) void gemm_sc(
    const u16* __restrict__ qk, u16* __restrict__ sb,
    float* __restrict__ lsum, const int* __restrict__ causalp) {
  __shared__ u16 As[16384];
  __shared__ u16 Bs[16384];
  const int causal = causalp[0];
  const int j = blockIdx.x;
  int zb, rt, ct;
  if (causal) {
    if (j >= 544) return;
    zb = j / 136;
    int i2 = j - zb * 136, r = 0;
    while (i2 >= r + 1) { i2 -= r + 1; ++r; }   // row-major lower triangle
    rt = r; ct = i2;
  } else {
    zb = j >> 8;
    const int rem = j & 255;
    rt = rem >> 4; ct = rem & 15;
  }
  gemm_core8<1>(rt, ct, zb, causal, As, Bs,
                qk, 2048LL * 2048, 2048, qk + 1024, 2048LL * 2048, 2048,
                sb, 2048LL * 2048, 2048, 1024, 0.03125f, lsum);
}

// ---------------------------------------------------------------------------
// PV: out[2048 x 1024] = (P' @ (V^T)^T) * rcp(lsum) per batch, fp32.
// Static r7 decode (complementary Keff pairing), 512-thread blocks.
// ---------------------------------------------------------------------------
__global__ __launch_bounds__(512) void gemm_pv(
    const u16* __restrict__ sb, const u16* __restrict__ vtb,
    float* __restrict__ out, float* __restrict__ lsum,
    const int* __restrict__ causalp) {
  __shared__ u16 As[16384];
  __shared__ u16 Bs[16384];
  const int causal = causalp[0];
  const int s = ((blockIdx.x & 7) << 6) + (blockIdx.x >> 3);
  const int zb = s >> 7;
  const int ct = (s & 127) >> 4;
  const int m = s & 15;
  const int rt = (s & 32) ? m : 15 - m;
  gemm_core8<2>(rt, ct, zb, causal, As, Bs,
                sb, 2048LL * 2048, 2048, vtb, 1024LL * 2048, 2048,
                out, 2048LL * 1024, 1024, 2048, 1.0f, lsum);
}

// ---------------------------------------------------------------------------
extern "C" void kernel_launch(void* const* d_in, const int* in_sizes, int n_in,
                              void* d_out, int out_size, void* d_ws, size_t ws_size,
                              hipStream_t stream) {
  const float* x  = (const float*)d_in[0];
  const float* wq = (const float*)d_in[1];
  const float* wk = (const float*)d_in[2];
  const float* wv = (const float*)d_in[3];
  const int* causal = (const int*)d_in[4];
  float* out = (float*)d_out;

  // workspace layout (bytes):
  //   xb 0..16,777,216   wb ..23,068,672   qk ..56,623,104
  //   vt ..73,400,320    sb ..106,954,752  lsum ..106,987,520
  char* ws = (char*)d_ws;
  u16* xb = (u16*)(ws);               // [8192][1024] bf16 x
  u16* wb = (u16*)(ws + 16777216);    // [3072][1024] bf16 Wq|Wk|Wv
  u16* qk = (u16*)(ws + 23068672);    // [8192][2048] bf16 Q|K
  u16* vt = (u16*)(ws + 56623104);    // [4][1024][2048] bf16 V^T
  u16* sb = (u16*)(ws + 73400320);    // [4][2048][2048] bf16 exp-scores
  float* lsum = (float*)(ws + 106954752);  // [4][2048] softmax denominators

  // casts (x, wq, wk, wv -> bf16) + lsum zero-init, one launch
  cast_all<<<11264, 256, 0, stream>>>(x, wq, wk, wv, xb, wb, lsum);

  // QKV: [8192 x 3072] = xb @ wb^T ; Q,K -> qk, V -> vt (transposed)
  gemm_nt<0><<<dim3(64, 24, 1), 256, 0, stream>>>(
      xb, 0, 1024, wb, 0, 1024, qk, 0, 2048, 1024, vt, 1.0f, nullptr, causal);

  // exp-scores: 512-thread blocks, grid 1024 (causal uses first 544)
  gemm_sc<<<dim3(1024, 1, 1), 512, 0, stream>>>(qk, sb, lsum, causal);

  // out per batch: [2048 x 1024] = (P' @ (V^T)^T) * rcp(lsum) -> fp32
  gemm_pv<<<dim3(512, 1, 1), 512, 0, stream>>>(sb, vt, out, lsum, causal);
}

// Round 10
// 231.312 us; speedup vs baseline: 1.0371x; 1.0371x over previous
//
#include <hip/hip_runtime.h>
#include <stdint.h>

typedef unsigned short u16;
typedef __attribute__((ext_vector_type(8))) __bf16 bf16x8;
typedef __attribute__((ext_vector_type(4))) float f32x4;

__device__ __forceinline__ u16 f2bf(float f) {
  unsigned u = __float_as_uint(f);
  u += 0x7FFF + ((u >> 16) & 1);   // RNE
  return (u16)(u >> 16);
}

__device__ __forceinline__ float bf2f(u16 h) {
  return __uint_as_float(((unsigned)h) << 16);
}

__device__ __forceinline__ void llds16(const u16* g, u16* l) {
  __builtin_amdgcn_global_load_lds(
      (const __attribute__((address_space(1))) void*)g,
      (__attribute__((address_space(3))) void*)l, 16, 0, 0);
}

// ---------------------------------------------------------------------------
// fused cast fp32 -> bf16 for x | wq | wk | wv + zero lsum
// ---------------------------------------------------------------------------
__global__ __launch_bounds__(256) void cast_all(
    const float* __restrict__ x, const float* __restrict__ wq,
    const float* __restrict__ wk, const float* __restrict__ wv,
    u16* __restrict__ xb, u16* __restrict__ wb, float* __restrict__ lsum) {
  int i = blockIdx.x * 256 + threadIdx.x;
  if (i < 8192) lsum[i] = 0.f;        // softmax-denominator accumulator
  const float* src; u16* dst; int off;
  if (i < 2097152)      { src = x;  dst = xb;            off = i; }
  else if (i < 2359296) { src = wq; dst = wb;            off = i - 2097152; }
  else if (i < 2621440) { src = wk; dst = wb + 1048576;  off = i - 2359296; }
  else                  { src = wv; dst = wb + 2097152;  off = i - 2621440; }
  float4 f = ((const float4*)src)[off];
  ushort4 o;
  o.x = f2bf(f.x); o.y = f2bf(f.y); o.z = f2bf(f.z); o.w = f2bf(f.w);
  ((ushort4*)dst)[off] = o;
}

// ---------------------------------------------------------------------------
// QKV GEMM (r0-verbatim gemm_nt, instantiated MODE 0 only).
// 128x128 tile, BK=64, 256 threads = 4 waves (2x2), each wave 64x64 via 4x4
// mfma_f32_16x16x32_bf16.  global_load_lds w16 staging, chunk-XOR swizzle
// (bank-conflict 0 measured).  ISOLATED template: sharing a core with sc/pv
// pushed VGPR 80->116 (r5, rule #19).  Measured 66.6us / 80 VGPR (r8, r9).
// Session ledger: 256^2 8-phase port SLOWER here (r1-2: grid quantization +
// short K).  Static decode permutations: zero delta twice (r3-4).  Work
// queues: only pay when jobs >> resident blocks (r8 pv: +9.4us).  8-wave
// blocks on 128^2 tile: +12us (r9: worse MFMA:ds_read ratio) — keep 64x64
// wave tiles.  sc/pv dbuf: -4.3us (r5->r7 clean A/B).
// ---------------------------------------------------------------------------
template<int MODE>
__global__ __launch_bounds__(256) void gemm_nt(
    const u16* __restrict__ A, long long sA, int lda,
    const u16* __restrict__ B, long long sB, int ldb,
    void* __restrict__ Cp, long long sC, int ldc,
    int K, u16* __restrict__ vt, float scale,
    float* __restrict__ lsum, const int* __restrict__ causalp) {
  const int t = threadIdx.x;
  const int causal = (MODE == 0) ? 1 : causalp[0];

  int rt = blockIdx.x, ct = blockIdx.y;

  const int rowbase = rt * 128;
  const int colbase = ct * 128;
  const u16* Ab = A + (long long)blockIdx.z * sA;
  const u16* Bb = B + (long long)blockIdx.z * sB;

  int Keff = K;
  if (MODE == 2 && causal) Keff = min(K, rowbase + 128);

  __shared__ u16 As[8192];   // [128][64] u16, chunk-swizzled
  __shared__ u16 Bs[8192];

  const int lane = t & 63;
  const int wv = t >> 6;
  const int wr = wv >> 1;
  const int wc = wv & 1;
  const int quad = lane >> 4;
  const int lr = lane & 15;

  f32x4 acc[4][4];
  const f32x4 zero = {0.f, 0.f, 0.f, 0.f};
#pragma unroll
  for (int i = 0; i < 4; ++i)
#pragma unroll
    for (int j = 0; j < 4; ++j) acc[i][j] = zero;

  {
    const int csw = (t & 7) ^ ((t >> 3) & 7);
    const u16* ga = Ab + (long long)(rowbase + (t >> 3)) * lda + csw * 8;
    const u16* gb = Bb + (long long)(colbase + (t >> 3)) * ldb + csw * 8;
    const long long ra = 32LL * lda, rb = 32LL * ldb;
    u16* la = As + t * 8;
    u16* lb = Bs + t * 8;

    const int m7 = lr & 7;
    const int a_base = (wr * 64 + lr) * 64 + ((quad ^ m7) * 8);
    const int b_base = (wc * 64 + lr) * 64 + ((quad ^ m7) * 8);

    for (int k0 = 0; k0 < Keff; k0 += 64) {
      __syncthreads();               // prior frag reads done before overwrite
#pragma unroll
      for (int i = 0; i < 4; ++i) {
        llds16(ga + k0 + i * ra, la + i * 2048);
        llds16(gb + k0 + i * rb, lb + i * 2048);
      }
      __syncthreads();               // compiler drains vmcnt before barrier
#pragma unroll
      for (int ks = 0; ks < 2; ++ks) {
        const int ko = ks ? 32 : 0;  // slot ^= 4  ->  u16 offset ^ 32
        bf16x8 af[4], bfv[4];
#pragma unroll
        for (int tm = 0; tm < 4; ++tm)
          af[tm] = *(const bf16x8*)(As + ((a_base + tm * 1024) ^ ko));
#pragma unroll
        for (int tn = 0; tn < 4; ++tn)
          bfv[tn] = *(const bf16x8*)(Bs + ((b_base + tn * 1024) ^ ko));
#pragma unroll
        for (int tm = 0; tm < 4; ++tm)
#pragma unroll
          for (int tn = 0; tn < 4; ++tn)
            acc[tm][tn] = __builtin_amdgcn_mfma_f32_16x16x32_bf16(
                af[tm], bfv[tn], acc[tm][tn], 0, 0, 0);
      }
    }
  }

  // ------------------------------ epilogue ------------------------------
  if (MODE == 0 && colbase >= 2048) {
#pragma unroll
    for (int tm = 0; tm < 4; ++tm) {
      int s0 = rowbase + wr * 64 + tm * 16 + quad * 4;
      int b = s0 >> 11;
      int sl = s0 & 2047;
#pragma unroll
      for (int tn = 0; tn < 4; ++tn) {
        int e = colbase - 2048 + wc * 64 + tn * 16 + lr;
        ushort4 o;
        o.x = f2bf(acc[tm][tn][0]);
        o.y = f2bf(acc[tm][tn][1]);
        o.z = f2bf(acc[tm][tn][2]);
        o.w = f2bf(acc[tm][tn][3]);
        *(ushort4*)(vt + ((long long)(b * 1024 + e)) * 2048 + sl) = o;
      }
    }
    return;
  }

#pragma unroll
  for (int tm = 0; tm < 4; ++tm) {
#pragma unroll
    for (int r = 0; r < 4; ++r) {
      const int grow = rowbase + wr * 64 + tm * 16 + quad * 4 + r;
      float li, rsum = 0.f;
      if (MODE == 2) li = __builtin_amdgcn_rcpf(lsum[blockIdx.z * 2048 + grow]);
#pragma unroll
      for (int tn = 0; tn < 4; ++tn) {
        const int gcol = colbase + wc * 64 + tn * 16 + lr;
        float val = acc[tm][tn][r];
        if (MODE == 0) {
          ((u16*)Cp)[(long long)grow * ldc + gcol] = f2bf(val);
        } else if (MODE == 1) {
          u16* C = (u16*)Cp + (long long)blockIdx.z * sC;
          float ex = (causal && gcol > grow) ? 0.f : __expf(val * scale);
          C[(long long)grow * ldc + gcol] = f2bf(ex);
          rsum += ex;
        } else {
          float* C = (float*)Cp + (long long)blockIdx.z * sC;
          C[(long long)grow * ldc + gcol] = val * li;
        }
      }
      if (MODE == 1) {
#pragma unroll
        for (int o = 8; o > 0; o >>= 1) rsum += __shfl_xor(rsum, o, 64);
        if (lr == 0)
          atomicAdd(&lsum[blockIdx.z * 2048 + grow], rsum);
      }
    }
  }
}

// ---------------------------------------------------------------------------
// sc/pv core: 4 waves (2x2), 64x64 wave tile, 128x128 block tile, BK=64,
// 2-phase DOUBLE-BUFFERED (r5->r7 clean A/B: -4.3us total vs single-buffer;
// r8/r9 correctness-verified).  {prefetch buf^1 -> compute buf -> barrier};
// compiler's vmcnt/lgkm drain at the barrier is the phase wait.
// MODE 1: scores -> exp(s*scale) fused, causal -> 0, row-sums atomicAdd
// MODE 2: PV -> fp32, * rcp(lsum[row]), causal K-truncation
// ---------------------------------------------------------------------------
template<int MODE>
__device__ __forceinline__ void gemm_core(
    int rt, int ct, int zb, int causal, u16* As, u16* Bs,
    const u16* __restrict__ A, long long sA, int lda,
    const u16* __restrict__ B, long long sB, int ldb,
    void* __restrict__ Cp, long long sC, int ldc,
    int K, float scale, float* __restrict__ lsum) {
  const int t = threadIdx.x;

  const int rowbase = rt * 128;
  const int colbase = ct * 128;
  const u16* Ab = A + (long long)zb * sA;
  const u16* Bb = B + (long long)zb * sB;

  int Keff = K;
  if (MODE == 2 && causal) Keff = min(K, rowbase + 128);

  const int lane = t & 63;
  const int wv = t >> 6;
  const int wr = wv >> 1;
  const int wc = wv & 1;
  const int quad = lane >> 4;
  const int lr = lane & 15;

  f32x4 acc[4][4];
  const f32x4 zero = {0.f, 0.f, 0.f, 0.f};
#pragma unroll
  for (int i = 0; i < 4; ++i)
#pragma unroll
    for (int j = 0; j < 4; ++j) acc[i][j] = zero;

  {
    const int csw = (t & 7) ^ ((t >> 3) & 7);
    const u16* ga = Ab + (long long)(rowbase + (t >> 3)) * lda + csw * 8;
    const u16* gb = Bb + (long long)(colbase + (t >> 3)) * ldb + csw * 8;
    const long long ra = 32LL * lda, rb = 32LL * ldb;
    u16* la = As + t * 8;
    u16* lb = Bs + t * 8;

    const int m7 = lr & 7;
    const int a_base = (wr * 64 + lr) * 64 + ((quad ^ m7) * 8);
    const int b_base = (wc * 64 + lr) * 64 + ((quad ^ m7) * 8);

    // ---- 2-phase double-buffered pipeline (buffers 8192 u16 apart) ----
#pragma unroll
    for (int i = 0; i < 4; ++i) {   // prologue: stage k=0 into buf0
      llds16(ga + i * ra, la + i * 2048);
      llds16(gb + i * rb, lb + i * 2048);
    }
    __syncthreads();
    for (int k0 = 0; k0 < Keff; k0 += 64) {
      const int nb = ((k0 >> 6) & 1) ^ 1;       // prefetch buffer
      const int bo = (nb ^ 1) << 13;            // current buffer offset
      if (k0 + 64 < Keff) {
#pragma unroll
        for (int i = 0; i < 4; ++i) {           // issue next-tile loads
          llds16(ga + (k0 + 64) + i * ra, la + nb * 8192 + i * 2048);
          llds16(gb + (k0 + 64) + i * rb, lb + nb * 8192 + i * 2048);
        }
      }
#pragma unroll
      for (int ks = 0; ks < 2; ++ks) {          // compute current buffer
        const int ko = ks ? 32 : 0;
        bf16x8 af[4], bfv[4];
#pragma unroll
        for (int tm = 0; tm < 4; ++tm)
          af[tm] = *(const bf16x8*)(As + bo + ((a_base + tm * 1024) ^ ko));
#pragma unroll
        for (int tn = 0; tn < 4; ++tn)
          bfv[tn] = *(const bf16x8*)(Bs + bo + ((b_base + tn * 1024) ^ ko));
#pragma unroll
        for (int tm = 0; tm < 4; ++tm)
#pragma unroll
          for (int tn = 0; tn < 4; ++tn)
            acc[tm][tn] = __builtin_amdgcn_mfma_f32_16x16x32_bf16(
                af[tm], bfv[tn], acc[tm][tn], 0, 0, 0);
      }
      __syncthreads();   // drains prefetch (vmcnt0) + orders buffer reuse
    }
  }

  // ------------------------------ epilogue ------------------------------
#pragma unroll
  for (int tm = 0; tm < 4; ++tm) {
#pragma unroll
    for (int r = 0; r < 4; ++r) {
      const int grow = rowbase + wr * 64 + tm * 16 + quad * 4 + r;
      float li, rsum = 0.f;
      if (MODE == 2) li = __builtin_amdgcn_rcpf(lsum[zb * 2048 + grow]);
#pragma unroll
      for (int tn = 0; tn < 4; ++tn) {
        const int gcol = colbase + wc * 64 + tn * 16 + lr;
        float val = acc[tm][tn][r];
        if (MODE == 1) {
          u16* C = (u16*)Cp + (long long)zb * sC;
          float ex = (causal && gcol > grow) ? 0.f : __expf(val * scale);
          C[(long long)grow * ldc + gcol] = f2bf(ex);
          rsum += ex;
        } else {
          float* C = (float*)Cp + (long long)zb * sC;
          C[(long long)grow * ldc + gcol] = val * li;
        }
      }
      if (MODE == 1) {
#pragma unroll
        for (int o = 8; o > 0; o >>= 1) rsum += __shfl_xor(rsum, o, 64);
        if (lr == 0)
          atomicAdd(&lsum[zb * 2048 + grow], rsum);
      }
    }
  }
}

// ---------------------------------------------------------------------------
// scores: P' = exp((Q @ K^T)/32), lower-tri tiles when causal, bf16 out;
// row sums -> lsum via atomics.  Static decode from bench r4 (best round):
// xcd = x&7, chunk rotated per batch; chunks 0..16 -> ct-major lower tri,
// 17..31 -> strict upper (instant return when causal).  Grid dim3(256,1,4).
// ---------------------------------------------------------------------------
__global__ __launch_bounds__(256) void gemm_sc(
    const u16* __restrict__ qk, u16* __restrict__ sb,
    float* __restrict__ lsum, const int* __restrict__ causalp) {
  __shared__ u16 As[16384];
  __shared__ u16 Bs[16384];
  const int causal = causalp[0];
  const int zb = blockIdx.z;
  const int xcd = blockIdx.x & 7;
  const int chunk = ((blockIdx.x >> 3) + 8 * blockIdx.z) & 31;
  int rt, ct;
  if (chunk < 17) {
    int i2 = xcd * 17 + chunk, c = 0;
    while (i2 >= 16 - c) { i2 -= 16 - c; ++c; }
    ct = c; rt = c + i2;                  // ct-major lower triangle
  } else {
    if (causal) return;                   // strict upper: never needed
    int i2 = xcd * 15 + (chunk - 17), r = 0;
    while (i2 >= r + 1) { i2 -= r + 1; ++r; }
    rt = i2; ct = r + 1;                  // strict upper tile
  }
  gemm_core<1>(rt, ct, zb, causal, As, Bs,
               qk, 2048LL * 2048, 2048, qk + 1024, 2048LL * 2048, 2048,
               sb, 2048LL * 2048, 2048, 1024, 0.03125f, lsum);
}

// ---------------------------------------------------------------------------
// PV: out[2048 x 1024] = (P' @ (V^T)^T) * rcp(lsum) per batch, fp32.
// Static decode from bench r4 (complementary-Keff pairing), grid 512.
// ---------------------------------------------------------------------------
__global__ __launch_bounds__(256) void gemm_pv(
    const u16* __restrict__ sb, const u16* __restrict__ vtb,
    float* __restrict__ out, float* __restrict__ lsum,
    const int* __restrict__ causalp) {
  __shared__ u16 As[16384];
  __shared__ u16 Bs[16384];
  const int causal = causalp[0];
  const int s = ((blockIdx.x & 7) << 6) + (blockIdx.x >> 3);
  const int zb = s >> 7;
  const int ct = (s & 127) >> 4;
  const int m = s & 15;
  const int rt = (s & 32) ? m : 15 - m;
  gemm_core<2>(rt, ct, zb, causal, As, Bs,
               sb, 2048LL * 2048, 2048, vtb, 1024LL * 2048, 2048,
               out, 2048LL * 1024, 1024, 2048, 1.0f, lsum);
}

// ---------------------------------------------------------------------------
extern "C" void kernel_launch(void* const* d_in, const int* in_sizes, int n_in,
                              void* d_out, int out_size, void* d_ws, size_t ws_size,
                              hipStream_t stream) {
  const float* x  = (const float*)d_in[0];
  const float* wq = (const float*)d_in[1];
  const float* wk = (const float*)d_in[2];
  const float* wv = (const float*)d_in[3];
  const int* causal = (const int*)d_in[4];
  float* out = (float*)d_out;

  // workspace layout (bytes):
  //   xb 0..16,777,216   wb ..23,068,672   qk ..56,623,104
  //   vt ..73,400,320    sb ..106,954,752  lsum ..106,987,520
  char* ws = (char*)d_ws;
  u16* xb = (u16*)(ws);               // [8192][1024] bf16 x
  u16* wb = (u16*)(ws + 16777216);    // [3072][1024] bf16 Wq|Wk|Wv
  u16* qk = (u16*)(ws + 23068672);    // [8192][2048] bf16 Q|K
  u16* vt = (u16*)(ws + 56623104);    // [4][1024][2048] bf16 V^T
  u16* sb = (u16*)(ws + 73400320);    // [4][2048][2048] bf16 exp-scores
  float* lsum = (float*)(ws + 106954752);  // [4][2048] softmax denominators

  // casts (x, wq, wk, wv -> bf16) + lsum zero-init, one launch
  cast_all<<<11264, 256, 0, stream>>>(x, wq, wk, wv, xb, wb, lsum);

  // QKV: [8192 x 3072] = xb @ wb^T ; Q,K -> qk, V -> vt (transposed)
  gemm_nt<0><<<dim3(64, 24, 1), 256, 0, stream>>>(
      xb, 0, 1024, wb, 0, 1024, qk, 0, 2048, 1024, vt, 1.0f, nullptr, causal);

  // exp-scores per batch: static triangular decode (r4), dbuf core
  gemm_sc<<<dim3(256, 1, 4), 256, 0, stream>>>(qk, sb, lsum, causal);

  // out per batch: [2048 x 1024] = (P' @ (V^T)^T) * rcp(lsum) -> fp32
  gemm_pv<<<dim3(512, 1, 1), 256, 0, stream>>>(sb, vt, out, lsum, causal);
}